// Round 2
// baseline (894.352 us; speedup 1.0000x reference)
//
#include <hip/hip_runtime.h>
#include <hip/hip_bf16.h>
#include <stdint.h>

#define B_ 2
#define N_ 8192
#define C_ 64
#define K_ 16
#define D_IN 131     // 2C+3
#define XS_STRIDE 168
#define TS 1024

typedef __attribute__((ext_vector_type(8))) short short8v;
typedef __attribute__((ext_vector_type(4))) float f32x4;

__device__ __forceinline__ float sq3(float x, float y, float z) {
#pragma clang fp contract(off)
  return (x * x + y * y) + z * z;
}

__device__ __forceinline__ uint64_t shfl_xor_u64(uint64_t x, int mask) {
  int lo = __shfl_xor((int)(uint32_t)(x & 0xffffffffull), mask, 64);
  int hi = __shfl_xor((int)(uint32_t)(x >> 32), mask, 64);
  return ((uint64_t)(uint32_t)hi << 32) | (uint32_t)lo;
}

// ---------------- KNN: 64 queries/block, 4 lanes/query ----------------
__global__ __launch_bounds__(256) void knn_kernel(const float* __restrict__ coords,
                                                  int* __restrict__ idxout) {
  __shared__ float4 cl[TS];
  const int t = threadIdx.x;
  const int blk = blockIdx.x;          // 256 blocks: 128 per batch
  const int bb = blk >> 7;
  const int qbase = (blk & 127) * 64;
  const float* cb = coords + (size_t)bb * N_ * 3;
  const int ql = t >> 2;
  const int s = t & 3;
  const int n = qbase + ql;
  const float qx = cb[n * 3 + 0], qy = cb[n * 3 + 1], qz = cb[n * 3 + 2];
  const float xxq = sq3(qx, qy, qz);

  uint64_t h[16];
#pragma unroll
  for (int i = 0; i < 16; ++i) h[i] = ~0ull;

  for (int j0 = 0; j0 < N_; j0 += TS) {
    __syncthreads();
#pragma unroll
    for (int i = 0; i < TS / 256; ++i) {
      int j = j0 + t + 256 * i;
      float cx = cb[j * 3 + 0], cy = cb[j * 3 + 1], cz = cb[j * 3 + 2];
      cl[t + 256 * i] = make_float4(cx, cy, cz, sq3(cx, cy, cz));
    }
    __syncthreads();
    for (int i = 0; i < TS / 4; ++i) {
      int c = s + i * 4;
      float4 cd = cl[c];
      float dot = fmaf(qz, cd.z, fmaf(qy, cd.y, qx * cd.x));
      float d2;
      {
#pragma clang fp contract(off)
        d2 = (xxq + cd.w) - 2.0f * dot;
      }
      d2 = fmaxf(d2, 0.0f);
      uint64_t key = ((uint64_t)__float_as_uint(d2) << 32) | (uint32_t)(j0 + c);
      if (key < h[15]) {
        h[15] = key;
#pragma unroll
        for (int z = 15; z > 0; --z) {
          if (h[z] < h[z - 1]) { uint64_t tmp = h[z - 1]; h[z - 1] = h[z]; h[z] = tmp; }
        }
      }
    }
  }

  // merge the 4 per-lane sorted lists -> global top-16 (ascending (dist,idx))
  int* myout = idxout + ((size_t)(bb * N_ + n)) * K_;
#pragma unroll
  for (int r = 0; r < 16; ++r) {
    uint64_t v = h[0];
    uint64_t o = shfl_xor_u64(v, 1); v = (o < v) ? o : v;
    o = shfl_xor_u64(v, 2); v = (o < v) ? o : v;
    bool win = (h[0] == v);
    if (win) {
#pragma unroll
      for (int z = 0; z < 15; ++z) h[z] = h[z + 1];
      h[15] = ~0ull;
    }
    if (s == 0) myout[r] = (int)(uint32_t)(v & 0xffffffffull);
  }
}

// ------------- W -> bf16 B-fragment layout: wfrag[nt][ks][lane][j] -------------
__global__ __launch_bounds__(256) void prep_w(const float* __restrict__ W,
                                              __hip_bfloat16* __restrict__ wfrag) {
  int i = blockIdx.x * 256 + threadIdx.x;
  if (i >= 4 * 5 * 64 * 8) return;
  int j = i & 7;
  int l = (i >> 3) & 63;
  int ks = (i >> 9) % 5;
  int nt = (i >> 9) / 5;
  int k = ks * 32 + (l >> 4) * 8 + j;
  int col = nt * 16 + (l & 15);
  float v = (k < D_IN) ? W[k * 64 + col] : 0.0f;
  wfrag[i] = __float2bfloat16(v);
}

// ---------------- stage 2: gather + (16x131)@(131x64) + relu + max_k ----------------
__global__ __launch_bounds__(256) void stage2(const float* __restrict__ coords,
                                              const float* __restrict__ feat,
                                              const int* __restrict__ idxbuf,
                                              const __hip_bfloat16* __restrict__ wfrag,
                                              const float* __restrict__ bias,
                                              float* __restrict__ out) {
  __shared__ __align__(16) __hip_bfloat16 xs[4][16][XS_STRIDE];
  const int t = threadIdx.x;
  const int w = t >> 6;
  const int lane = t & 63;
  const int q = blockIdx.x * 4 + w;
  const int bb = q >> 13;
  const int n = q & (N_ - 1);
  const float* cb = coords + (size_t)bb * N_ * 3;
  const float* fb = feat + (size_t)bb * N_ * C_;
  const int* myidx = idxbuf + (size_t)q * K_;

  float fi = fb[(size_t)n * C_ + lane];
  float qc = (lane < 3) ? cb[n * 3 + lane] : 0.0f;

#pragma unroll
  for (int k = 0; k < K_; ++k) {
    int nb = myidx[k];
    float nf = fb[(size_t)nb * C_ + lane];
    xs[w][k][lane] = __float2bfloat16(fi);
    xs[w][k][C_ + lane] = __float2bfloat16(nf - fi);
    if (lane < 3) {
      xs[w][k][128 + lane] = __float2bfloat16(cb[nb * 3 + lane] - qc);
    } else if (lane < 40) {
      xs[w][k][128 + lane] = __float2bfloat16(0.0f);  // zero-pad d = 131..167
    }
  }
  __syncthreads();

  const int row = lane & 15;   // = output channel within 16-col tile (D's col)
  const int g = lane >> 4;
  short8v a[5];
#pragma unroll
  for (int ks = 0; ks < 5; ++ks)
    a[ks] = *(const short8v*)&xs[w][row][ks * 32 + g * 8];

  const short8v* wf = (const short8v*)wfrag;
#pragma unroll
  for (int nt = 0; nt < 4; ++nt) {
    f32x4 acc = {0.f, 0.f, 0.f, 0.f};
#pragma unroll
    for (int ks = 0; ks < 5; ++ks) {
      short8v bf = wf[(nt * 5 + ks) * 64 + lane];
      acc = __builtin_amdgcn_mfma_f32_16x16x32_bf16(a[ks], bf, acc, 0, 0, 0);
    }
    float bcol = bias[nt * 16 + row];
    float m = fmaxf(fmaxf(fmaxf(acc[0] + bcol, 0.f), fmaxf(acc[1] + bcol, 0.f)),
                    fmaxf(fmaxf(acc[2] + bcol, 0.f), fmaxf(acc[3] + bcol, 0.f)));
    m = fmaxf(m, __shfl_xor(m, 16, 64));
    m = fmaxf(m, __shfl_xor(m, 32, 64));
    if (lane < 16) out[(size_t)q * C_ + nt * 16 + row] = m;
  }
}

extern "C" void kernel_launch(void* const* d_in, const int* in_sizes, int n_in,
                              void* d_out, int out_size, void* d_ws, size_t ws_size,
                              hipStream_t stream) {
  const float* coords = (const float*)d_in[0];
  const float* feat = (const float*)d_in[1];
  const float* W = (const float*)d_in[2];
  const float* bias = (const float*)d_in[3];
  float* out = (float*)d_out;

  int* ws_idx = (int*)d_ws;  // B*N*K ints = 1 MiB
  __hip_bfloat16* wfrag = (__hip_bfloat16*)((char*)d_ws + (size_t)B_ * N_ * K_ * sizeof(int));

  prep_w<<<(4 * 5 * 64 * 8 + 255) / 256, 256, 0, stream>>>(W, wfrag);
  knn_kernel<<<256, 256, 0, stream>>>(coords, ws_idx);
  stage2<<<(B_ * N_) / 4, 256, 0, stream>>>(coords, feat, ws_idx, wfrag, bias, out);
}

// Round 4
// 264.425 us; speedup vs baseline: 3.3823x; 3.3823x over previous
//
#include <hip/hip_runtime.h>
#include <hip/hip_bf16.h>
#include <stdint.h>

#define B_ 2
#define N_ 8192
#define C_ 64
#define K_ 16
#define D_IN 131     // 2C+3
#define XS_STRIDE 168
#define TS 1024
#define L_ 16        // lanes per query
#define QPB 16       // queries per block (256 threads)

typedef __attribute__((ext_vector_type(8))) short short8v;
typedef __attribute__((ext_vector_type(4))) float f32x4;

// sentinel: larger than any real key, but FINITE as f64 (all-ones would be NaN
// and v_min_f64/v_max_f64 drop NaNs -> corrupt list)
#define SENT_U64 0x7F7FFFFFFFFFFFFFull

__device__ __forceinline__ float sq3(float x, float y, float z) {
#pragma clang fp contract(off)
  return (x * x + y * y) + z * z;
}

__device__ __forceinline__ uint64_t shfl_xor_u64(uint64_t x, int mask) {
  int lo = __shfl_xor((int)(uint32_t)(x & 0xffffffffull), mask, 64);
  int hi = __shfl_xor((int)(uint32_t)(x >> 32), mask, 64);
  return ((uint64_t)(uint32_t)hi << 32) | (uint32_t)lo;
}

__device__ __forceinline__ double shfl_xor_f64(double x, int mask) {
  return __builtin_bit_cast(double, shfl_xor_u64(__builtin_bit_cast(uint64_t, x), mask));
}

// branchless sorted-insert: precondition key < hd[15]; one bubble pass with
// v_min_f64/v_max_f64 (2 insts per stage, 15 stages)
__device__ __forceinline__ void insert16(double* hd, double key) {
  hd[15] = key;
#pragma unroll
  for (int z = 15; z >= 1; --z) {
    double a = hd[z - 1], b = hd[z];
    hd[z - 1] = fmin(a, b);
    hd[z] = fmax(a, b);
  }
}

// ---------------- KNN: 16 queries/block, 16 lanes/query, 1024 blocks ----------------
__global__ __launch_bounds__(256) void knn_kernel(const float* __restrict__ coords,
                                                  int* __restrict__ idxout) {
  __shared__ float4 cl[TS];
  const int t = threadIdx.x;
  const int blk = blockIdx.x;          // 1024 blocks: 512 per batch
  const int bb = blk >> 9;
  const int qbase = (blk & 511) * QPB;
  const float* cb = coords + (size_t)bb * N_ * 3;
  const int ql = t >> 4;               // 0..15: query within block
  const int s = t & 15;                // lane within query group
  const int n = qbase + ql;
  const float qx = cb[n * 3 + 0], qy = cb[n * 3 + 1], qz = cb[n * 3 + 2];
  const float xxq = sq3(qx, qy, qz);

  double hd[16];
#pragma unroll
  for (int i = 0; i < 16; ++i) hd[i] = __builtin_bit_cast(double, SENT_U64);

  for (int j0 = 0; j0 < N_; j0 += TS) {
    __syncthreads();
#pragma unroll
    for (int i = 0; i < TS / 256; ++i) {
      int j = j0 + t + 256 * i;
      float cx = cb[j * 3 + 0], cy = cb[j * 3 + 1], cz = cb[j * 3 + 2];
      cl[t + 256 * i] = make_float4(cx, cy, cz, sq3(cx, cy, cz));
    }
    __syncthreads();
    for (int i = 0; i < TS / L_; i += 2) {
      int c0 = s + i * L_;
      int c1 = c0 + L_;
      float4 cd0 = cl[c0];
      float4 cd1 = cl[c1];
      float dot0 = fmaf(qz, cd0.z, fmaf(qy, cd0.y, qx * cd0.x));
      float dot1 = fmaf(qz, cd1.z, fmaf(qy, cd1.y, qx * cd1.x));
      float d20, d21;
      {
#pragma clang fp contract(off)
        d20 = (xxq + cd0.w) - 2.0f * dot0;
        d21 = (xxq + cd1.w) - 2.0f * dot1;
      }
      d20 = fmaxf(d20, 0.0f);
      d21 = fmaxf(d21, 0.0f);
      uint64_t u0 = ((uint64_t)__float_as_uint(d20) << 32) | (uint32_t)(j0 + c0);
      uint64_t u1 = ((uint64_t)__float_as_uint(d21) << 32) | (uint32_t)(j0 + c1);
      double k0 = __builtin_bit_cast(double, u0);
      double k1 = __builtin_bit_cast(double, u1);
      if (fmin(k0, k1) < hd[15]) {
        if (k0 < hd[15]) insert16(hd, k0);
        if (k1 < hd[15]) insert16(hd, k1);
      }
    }
  }

  // merge the 16 per-lane sorted lists -> global top-16 (ascending (dist,idx))
  int* myout = idxout + ((size_t)(bb * N_ + n)) * K_;
#pragma unroll
  for (int r = 0; r < 16; ++r) {
    double v = hd[0];
    v = fmin(v, shfl_xor_f64(v, 1));
    v = fmin(v, shfl_xor_f64(v, 2));
    v = fmin(v, shfl_xor_f64(v, 4));
    v = fmin(v, shfl_xor_f64(v, 8));
    if (__builtin_bit_cast(uint64_t, hd[0]) == __builtin_bit_cast(uint64_t, v)) {
#pragma unroll
      for (int z = 0; z < 15; ++z) hd[z] = hd[z + 1];
      hd[15] = __builtin_bit_cast(double, SENT_U64);
    }
    if (s == 0) myout[r] = (int)(uint32_t)__builtin_bit_cast(uint64_t, v);
  }
}

// ------------- W -> bf16 B-fragment layout: wfrag[nt][ks][lane][j] -------------
__global__ __launch_bounds__(256) void prep_w(const float* __restrict__ W,
                                              __hip_bfloat16* __restrict__ wfrag) {
  int i = blockIdx.x * 256 + threadIdx.x;
  if (i >= 4 * 5 * 64 * 8) return;
  int j = i & 7;
  int l = (i >> 3) & 63;
  int ks = (i >> 9) % 5;
  int nt = (i >> 9) / 5;
  int k = ks * 32 + (l >> 4) * 8 + j;
  int col = nt * 16 + (l & 15);
  float v = (k < D_IN) ? W[k * 64 + col] : 0.0f;
  wfrag[i] = __float2bfloat16(v);
}

// ---------------- stage 2: gather + (16x131)@(131x64) + relu + max_k ----------------
__global__ __launch_bounds__(256) void stage2(const float* __restrict__ coords,
                                              const float* __restrict__ feat,
                                              const int* __restrict__ idxbuf,
                                              const __hip_bfloat16* __restrict__ wfrag,
                                              const float* __restrict__ bias,
                                              float* __restrict__ out) {
  __shared__ __align__(16) __hip_bfloat16 xs[4][16][XS_STRIDE];
  const int t = threadIdx.x;
  const int w = t >> 6;
  const int lane = t & 63;
  const int q = blockIdx.x * 4 + w;
  const int bb = q >> 13;
  const int n = q & (N_ - 1);
  const float* cb = coords + (size_t)bb * N_ * 3;
  const float* fb = feat + (size_t)bb * N_ * C_;
  const int* myidx = idxbuf + (size_t)q * K_;

  float fi = fb[(size_t)n * C_ + lane];
  float qc = (lane < 3) ? cb[n * 3 + lane] : 0.0f;

#pragma unroll
  for (int k = 0; k < K_; ++k) {
    int nb = myidx[k];
    float nf = fb[(size_t)nb * C_ + lane];
    xs[w][k][lane] = __float2bfloat16(fi);
    xs[w][k][C_ + lane] = __float2bfloat16(nf - fi);
    if (lane < 3) {
      xs[w][k][128 + lane] = __float2bfloat16(cb[nb * 3 + lane] - qc);
    } else if (lane < 40) {
      xs[w][k][128 + lane] = __float2bfloat16(0.0f);  // zero-pad d = 131..167
    }
  }
  __syncthreads();

  const int row = lane & 15;   // = output channel within 16-col tile (D's col)
  const int g = lane >> 4;
  short8v a[5];
#pragma unroll
  for (int ks = 0; ks < 5; ++ks)
    a[ks] = *(const short8v*)&xs[w][row][ks * 32 + g * 8];

  const short8v* wf = (const short8v*)wfrag;
#pragma unroll
  for (int nt = 0; nt < 4; ++nt) {
    f32x4 acc = {0.f, 0.f, 0.f, 0.f};
#pragma unroll
    for (int ks = 0; ks < 5; ++ks) {
      short8v bf = wf[(nt * 5 + ks) * 64 + lane];
      acc = __builtin_amdgcn_mfma_f32_16x16x32_bf16(a[ks], bf, acc, 0, 0, 0);
    }
    float bcol = bias[nt * 16 + row];
    float m = fmaxf(fmaxf(fmaxf(acc[0] + bcol, 0.f), fmaxf(acc[1] + bcol, 0.f)),
                    fmaxf(fmaxf(acc[2] + bcol, 0.f), fmaxf(acc[3] + bcol, 0.f)));
    m = fmaxf(m, __shfl_xor(m, 16, 64));
    m = fmaxf(m, __shfl_xor(m, 32, 64));
    if (lane < 16) out[(size_t)q * C_ + nt * 16 + row] = m;
  }
}

extern "C" void kernel_launch(void* const* d_in, const int* in_sizes, int n_in,
                              void* d_out, int out_size, void* d_ws, size_t ws_size,
                              hipStream_t stream) {
  const float* coords = (const float*)d_in[0];
  const float* feat = (const float*)d_in[1];
  const float* W = (const float*)d_in[2];
  const float* bias = (const float*)d_in[3];
  float* out = (float*)d_out;

  int* ws_idx = (int*)d_ws;  // B*N*K ints = 1 MiB
  __hip_bfloat16* wfrag = (__hip_bfloat16*)((char*)d_ws + (size_t)B_ * N_ * K_ * sizeof(int));

  prep_w<<<(4 * 5 * 64 * 8 + 255) / 256, 256, 0, stream>>>(W, wfrag);
  knn_kernel<<<(B_ * N_) / QPB, 256, 0, stream>>>(coords, ws_idx);
  stage2<<<(B_ * N_) / 4, 256, 0, stream>>>(coords, feat, ws_idx, wfrag, bias, out);
}